// Round 14
// baseline (444.362 us; speedup 1.0000x reference)
//
#include <hip/hip_runtime.h>
#include <math.h>

typedef _Float16 f16;
typedef _Float16 h8  __attribute__((ext_vector_type(8)));
typedef _Float16 h4  __attribute__((ext_vector_type(4)));
typedef float    f4  __attribute__((ext_vector_type(4)));

#define N_NODES 100000
#define N_EDGES 1600000
#define FDIM    128
#define CDIM    20
#define NEG_SLOPE 0.01f

#define NPART 782                    // partitions of 128 dst nodes
#define PCAP  2560                   // static region per partition (mean 2046, +11 sigma)
#define NB    256                    // histogram/scatter blocks
#define EPB   (N_EDGES / NB)         // 6250 edges per block
#define PBUF  2944                   // repack LDS capacity
#define GATHER_BLOCKS (N_NODES * 32 / 256)   // 12500
#define GP    136                    // LDS pitch in halves

// ---------------------------------------------------------------------------
// K1 (fused): [0,NB) per-block dst-partition histograms (LDS atomics);
// [NB, NB+GATHER) emb-row gather fp32->fp16 into xA; then 128 blocks
// transpose W0/W1 to fp16 [n][k]; last 16 blocks build W2T (32x128, padded).
// ---------------------------------------------------------------------------
__global__ __launch_bounds__(256) void k1_build(const int* __restrict__ ids,
                                                const float* __restrict__ emb,
                                                f16* __restrict__ X,
                                                const int* __restrict__ dst,
                                                int* __restrict__ histG,
                                                const float* __restrict__ W0,
                                                const float* __restrict__ W1,
                                                const float* __restrict__ W2,
                                                f16* __restrict__ W0T,
                                                f16* __restrict__ W1T,
                                                f16* __restrict__ W2T) {
    int b = blockIdx.x, t = threadIdx.x;
    if (b < NB) {
        __shared__ unsigned lh[NPART];
        for (int i = t; i < NPART; i += 256) lh[i] = 0;
        __syncthreads();
        int e0 = b * EPB;
        for (int i = t; i < EPB; i += 256)
            atomicAdd(&lh[dst[e0 + i] >> 7], 1u);
        __syncthreads();
        for (int i = t; i < NPART; i += 256) histG[b * NPART + i] = (int)lh[i];
    } else if (b < NB + GATHER_BLOCKS) {
        int gid = (b - NB) * 256 + t;                 // N*32 exact
        int n = gid >> 5, qq = gid & 31;
        int v = ids[n];
        float4 vv = ((const float4*)emb)[(size_t)v * 32 + qq];
        h4 o; o[0] = (f16)vv.x; o[1] = (f16)vv.y; o[2] = (f16)vv.z; o[3] = (f16)vv.w;
        ((h4*)X)[(size_t)n * 32 + qq] = o;
    } else if (b < NB + GATHER_BLOCKS + 128) {
        int o = (b - NB - GATHER_BLOCKS) * 256 + t;   // 32768 total
        const float* W = (o < 16384) ? W0 : W1;
        f16* T = (o < 16384) ? W0T : W1T;
        int o2 = o & 16383;
        int n = o2 >> 7, k = o2 & 127;
        T[o2] = (f16)W[k * 128 + n];
    } else {
        int o = (b - NB - GATHER_BLOCKS - 128) * 256 + t;   // 4096 total
        int cc = o >> 7, k = o & 127;
        W2T[o] = (cc < CDIM) ? (f16)W2[k * CDIM + cc] : (f16)0.f;
    }
}

// ---------------------------------------------------------------------------
// K2: one wave per partition; static region base = p*PCAP (no global scan).
// Wave-scan the 256 per-block counts -> seed offsets; write ptot[p].
// ---------------------------------------------------------------------------
__global__ __launch_bounds__(256) void k2_seed(int* __restrict__ histG,
                                               int* __restrict__ ptot) {
    int w = blockIdx.x * 4 + (threadIdx.x >> 6);
    if (w >= NPART) return;
    int lane = threadIdx.x & 63;
    int base = w * PCAP;
    int v[4], pre[4], s = 0;
    #pragma unroll
    for (int i = 0; i < 4; ++i) v[i] = histG[(lane * 4 + i) * NPART + w];
    #pragma unroll
    for (int i = 0; i < 4; ++i) { pre[i] = s; s += v[i]; }
    int ss = s;
    #pragma unroll
    for (int off = 1; off < 64; off <<= 1) {
        int u = __shfl_up(ss, off);
        if (lane >= off) ss += u;
    }
    if (lane == 63) ptot[w] = ss;                     // partition total
    int wexcl = ss - s;
    #pragma unroll
    for (int i = 0; i < 4; ++i)
        histG[(lane * 4 + i) * NPART + w] = base + wexcl + pre[i];
}

// ---------------------------------------------------------------------------
// K3: deterministic scatter via LDS cursors seeded from exact offsets.
//   rec = ((dl<<17)|src, ew_f32); region-bound guard vs PCAP overflow.
// ---------------------------------------------------------------------------
__global__ __launch_bounds__(256) void k3_scatter(const int* __restrict__ src,
                                                  const int* __restrict__ dst,
                                                  const float* __restrict__ ew,
                                                  const int* __restrict__ histG,
                                                  uint2* __restrict__ recs) {
    __shared__ unsigned cur[NPART];
    int b = blockIdx.x, t = threadIdx.x;
    for (int i = t; i < NPART; i += 256) cur[i] = (unsigned)histG[b * NPART + i];
    __syncthreads();
    int e0 = b * EPB;
    for (int i = t; i < EPB; i += 256) {
        int e = e0 + i;
        int s = src[e], d = dst[e];
        int p = d >> 7, dl = d & 127;
        unsigned pos = atomicAdd(&cur[p], 1u);        // LDS atomic only
        if (pos < (unsigned)((p + 1) * PCAP)) {       // ~1e-20 overflow guard
            uint2 r; r.x = ((unsigned)dl << 17) | (unsigned)s; r.y = __float_as_uint(ew[e]);
            recs[pos] = r;
        }
    }
}

// ---------------------------------------------------------------------------
// K4: per-partition repack: sort records by dst_local in LDS, emit
// nstart/ncnt, weighted degree -> dinv. Strips dl from rec.x.
// ---------------------------------------------------------------------------
__global__ __launch_bounds__(256) void k4_repack(uint2* __restrict__ recs,
                                                 const int* __restrict__ ptot,
                                                 int* __restrict__ nstart,
                                                 int* __restrict__ ncnt,
                                                 float* __restrict__ dinv) {
    __shared__ uint2    buf[PBUF];                    // 23.5 KB
    __shared__ float    wsum[128];
    __shared__ unsigned hcnt[128], pref[128], cur[128];
    int p = blockIdx.x, t = threadIdx.x;
    if (t < 128) { hcnt[t] = 0; wsum[t] = 0.f; }
    __syncthreads();
    int base = p * PCAP;
    int c = ptot[p];
    if (c > PCAP) c = PCAP;
    for (int i = t; i < c; i += 256) {
        uint2 r = recs[base + i];
        buf[i] = r;
        int dl = r.x >> 17;
        atomicAdd(&hcnt[dl], 1u);
        atomicAdd(&wsum[dl], __uint_as_float(r.y));
    }
    __syncthreads();
    if (t == 0) {
        unsigned s = 0;
        for (int k = 0; k < 128; ++k) { pref[k] = s; s += hcnt[k]; }
    }
    __syncthreads();
    if (t < 128) {
        cur[t] = pref[t];
        int g = p * 128 + t;
        if (g < N_NODES) {
            nstart[g] = base + (int)pref[t];
            ncnt[g]   = (int)hcnt[t];
            dinv[g]   = rsqrtf(wsum[t] + 1.0f);
        }
    }
    __syncthreads();
    for (int i = t; i < c; i += 256) {
        uint2 r = buf[i];
        int dl = r.x >> 17;
        unsigned pos = atomicAdd(&cur[dl], 1u);
        uint2 o; o.x = r.x & 0x1FFFFu; o.y = r.y;
        recs[base + pos] = o;
    }
}

// ---------------------------------------------------------------------------
// agg helper with HAND-WRITTEN 2-deep software pipeline (R13 lesson: the
// compiler will not pipeline the rec->row chain across batches on its own —
// unroll pragmas left VGPR=32/VALU=37%). Per iteration:
//   1. load ROWS for batch j+8   (rec already resolved, loaded last iter)
//   2. load REC  for batch j+16
//   3. FMA batch j with rows loaded a FULL iteration ago
// Row latency hidden by one whole FMA batch; rec latency by two.
// ---------------------------------------------------------------------------
__device__ __forceinline__ void agg_to_lds(const f16* __restrict__ Xi,
                                           const float* __restrict__ dinv,
                                           const int* __restrict__ nstart,
                                           const int* __restrict__ ncnt,
                                           const uint2* __restrict__ recs,
                                           f16* __restrict__ Xs,
                                           int wave, int lane, int nb) {
    int g = lane >> 3, l7 = lane & 7;
    for (int nn = 0; nn < 8; ++nn) {
        int node = nb + nn;
        int st = nstart[node], c = ncnt[node];
        float acc[16];
        #pragma unroll
        for (int k = 0; k < 16; ++k) acc[k] = 0.f;

        // prologue: rec+rows+coef for batch 0; rec for batch 1
        int j0 = (g < c) ? g : (c - 1);               // clamped (c==0 -> harmless ws read)
        uint2 r0 = recs[st + j0];
        const f16* rp0 = Xi + (size_t)r0.x * 128 + l7 * 16;
        h8 hA0 = *(const h8*)rp0;
        h8 hA1 = *(const h8*)(rp0 + 8);
        float ccA = (g < c) ? dinv[r0.x] * __uint_as_float(r0.y) : 0.f;
        int j1 = (8 + g < c) ? (8 + g) : (c > 0 ? c - 1 : 0);
        uint2 rC = recs[st + j1];

        for (int j = 0; j < c; j += 8) {
            // 1. rows for batch j+8 (rec rC resolved last iter)
            const f16* rpn = Xi + (size_t)rC.x * 128 + l7 * 16;
            h8 hB0 = *(const h8*)rpn;
            h8 hB1 = *(const h8*)(rpn + 8);
            float ccB = (j + 8 + g < c) ? dinv[rC.x] * __uint_as_float(rC.y) : 0.f;
            // 2. rec for batch j+16
            int jn = j + 16 + g;
            uint2 rN = recs[st + (jn < c ? jn : c - 1)];
            // 3. FMA batch j (hA loaded a full iteration ago)
            #pragma unroll
            for (int k = 0; k < 8; ++k) acc[k]     += ccA * (float)hA0[k];
            #pragma unroll
            for (int k = 0; k < 8; ++k) acc[k + 8] += ccA * (float)hA1[k];
            // rotate
            hA0 = hB0; hA1 = hB1; ccA = ccB; rC = rN;
        }
        #pragma unroll
        for (int k = 0; k < 16; ++k) {
            acc[k] += __shfl_xor(acc[k], 8);
            acc[k] += __shfl_xor(acc[k], 16);
            acc[k] += __shfl_xor(acc[k], 32);
        }
        if (g == 0) {
            float dn = dinv[node], d2 = dn * dn;
            const f16* sp = Xi + (size_t)node * 128 + l7 * 16;
            h8 s0 = *(const h8*)sp;
            h8 s1 = *(const h8*)(sp + 8);
            h8 o0, o1;
            #pragma unroll
            for (int k = 0; k < 8; ++k) o0[k] = (f16)(dn * acc[k]     + d2 * (float)s0[k]);
            #pragma unroll
            for (int k = 0; k < 8; ++k) o1[k] = (f16)(dn * acc[k + 8] + d2 * (float)s1[k]);
            f16* zp = Xs + (wave * 8 + nn) * GP + l7 * 16;
            *(h8*)zp = o0;
            *(h8*)(zp + 8) = o1;
        }
    }
}

// ---------------------------------------------------------------------------
// fusedL0: 256 thr / 32 nodes. Agg -> LDS z (8.5 KB; W stays in global,
// L1-resident). Then 32x128 @ 128x128 MFMA; leaky(+b) -> Xo.
// ---------------------------------------------------------------------------
__global__ __launch_bounds__(256, 8) void fusedL0(const f16* __restrict__ Xi,
                                                  const float* __restrict__ dinv,
                                                  const int* __restrict__ nstart,
                                                  const int* __restrict__ ncnt,
                                                  const uint2* __restrict__ recs,
                                                  const f16* __restrict__ WT,
                                                  const float* __restrict__ bias,
                                                  f16* __restrict__ Xo) {
    __shared__ f16 Xs[32 * GP];                       // 8.5 KB
    int t = threadIdx.x;
    int wave = t >> 6, lane = t & 63;
    agg_to_lds(Xi, dinv, nstart, ncnt, recs, Xs, wave, lane,
               blockIdx.x * 32 + wave * 8);
    __syncthreads();

    int quad = lane >> 4, l15 = lane & 15;
    int mtile = wave & 1, nh = wave >> 1;             // 2 m-tiles x 2 n-halves
    f4 a4[4]; f4 zero = {0.f, 0.f, 0.f, 0.f};
    #pragma unroll
    for (int i = 0; i < 4; ++i) a4[i] = zero;
    #pragma unroll
    for (int kk = 0; kk < 128; kk += 32) {
        h8 a = *(h8*)(Xs + (mtile * 16 + l15) * GP + kk + quad * 8);
        #pragma unroll
        for (int nt4 = 0; nt4 < 4; ++nt4) {
            int nt = nh * 4 + nt4;
            h8 b = *(const h8*)(WT + (nt * 16 + l15) * 128 + kk + quad * 8);
            a4[nt4] = __builtin_amdgcn_mfma_f32_16x16x32_f16(a, b, a4[nt4], 0, 0, 0);
        }
    }
    size_t rbase = (size_t)blockIdx.x * 32;
    #pragma unroll
    for (int nt4 = 0; nt4 < 4; ++nt4) {
        int col = (nh * 4 + nt4) * 16 + l15;
        float bb = bias[col];
        #pragma unroll
        for (int r = 0; r < 4; ++r) {
            size_t row = rbase + mtile * 16 + quad * 4 + r;
            float v = a4[nt4][r] + bb;
            v = v > 0.f ? v : NEG_SLOPE * v;
            Xo[row * 128 + col] = (f16)v;
        }
    }
}

// ---------------------------------------------------------------------------
// fusedL1: as fusedL0 + 128->20 GEMM in the epilogue (x2 via LDS, W2T from
// global, y stride-32). x2 never touches HBM.
// ---------------------------------------------------------------------------
__global__ __launch_bounds__(256, 8) void fusedL1(const f16* __restrict__ Xi,
                                                  const float* __restrict__ dinv,
                                                  const int* __restrict__ nstart,
                                                  const int* __restrict__ ncnt,
                                                  const uint2* __restrict__ recs,
                                                  const f16* __restrict__ WT,
                                                  const float* __restrict__ bias,
                                                  const f16* __restrict__ W2T,
                                                  f16* __restrict__ Y) {
    __shared__ f16 Xs[32 * GP];
    int t = threadIdx.x;
    int wave = t >> 6, lane = t & 63;
    agg_to_lds(Xi, dinv, nstart, ncnt, recs, Xs, wave, lane,
               blockIdx.x * 32 + wave * 8);
    __syncthreads();

    int quad = lane >> 4, l15 = lane & 15;
    int mtile = wave & 1, nh = wave >> 1;
    f4 a4[4]; f4 zero = {0.f, 0.f, 0.f, 0.f};
    #pragma unroll
    for (int i = 0; i < 4; ++i) a4[i] = zero;
    #pragma unroll
    for (int kk = 0; kk < 128; kk += 32) {
        h8 a = *(h8*)(Xs + (mtile * 16 + l15) * GP + kk + quad * 8);
        #pragma unroll
        for (int nt4 = 0; nt4 < 4; ++nt4) {
            int nt = nh * 4 + nt4;
            h8 b = *(const h8*)(WT + (nt * 16 + l15) * 128 + kk + quad * 8);
            a4[nt4] = __builtin_amdgcn_mfma_f32_16x16x32_f16(a, b, a4[nt4], 0, 0, 0);
        }
    }
    __syncthreads();                                  // z reads done
    #pragma unroll
    for (int nt4 = 0; nt4 < 4; ++nt4) {               // x2 = leaky(acc+b) -> LDS
        int col = (nh * 4 + nt4) * 16 + l15;
        float bb = bias[col];
        #pragma unroll
        for (int r = 0; r < 4; ++r) {
            float v = a4[nt4][r] + bb;
            v = v > 0.f ? v : NEG_SLOPE * v;
            Xs[(mtile * 16 + quad * 4 + r) * GP + col] = (f16)v;
        }
    }
    __syncthreads();
    int mt2 = wave & 1, nt2 = wave >> 1;              // 32x32 y tile, 4 waves
    f4 ya = zero;
    #pragma unroll
    for (int kk = 0; kk < 128; kk += 32) {
        h8 a = *(h8*)(Xs + (mt2 * 16 + l15) * GP + kk + quad * 8);
        h8 b = *(const h8*)(W2T + (nt2 * 16 + l15) * 128 + kk + quad * 8);
        ya = __builtin_amdgcn_mfma_f32_16x16x32_f16(a, b, ya, 0, 0, 0);
    }
    size_t rbase = (size_t)blockIdx.x * 32;
    #pragma unroll
    for (int r = 0; r < 4; ++r) {
        size_t row = rbase + mt2 * 16 + quad * 4 + r;
        Y[row * 32 + nt2 * 16 + l15] = (f16)ya[r];
    }
}

// ---------------------------------------------------------------------------
// agg20L: out = LSM( b2 + dn*sum(dinv[s]*ew*Y[s]) + dn^2*Y[n] ).
// Same hand-pipelined 2-deep structure (h4 loads of the padded 64B row).
// ---------------------------------------------------------------------------
__global__ __launch_bounds__(256) void agg20L(const f16* __restrict__ Y,
                                              const float* __restrict__ dinv,
                                              const int* __restrict__ nstart,
                                              const int* __restrict__ ncnt,
                                              const uint2* __restrict__ recs,
                                              const float* __restrict__ b2,
                                              float* __restrict__ out) {
    int wave = threadIdx.x >> 6, lane = threadIdx.x & 63;
    int g = lane >> 3, l7 = lane & 7;
    int node = blockIdx.x * 4 + wave;
    int st = nstart[node], c = ncnt[node];
    float acc[4];
    #pragma unroll
    for (int k = 0; k < 4; ++k) acc[k] = 0.f;

    int j0 = (g < c) ? g : (c - 1);
    uint2 r0 = recs[st + j0];
    h4 hA = *(const h4*)(Y + (size_t)r0.x * 32 + l7 * 4);
    float ccA = (g < c) ? dinv[r0.x] * __uint_as_float(r0.y) : 0.f;
    int j1 = (8 + g < c) ? (8 + g) : (c > 0 ? c - 1 : 0);
    uint2 rC = recs[st + j1];

    for (int j = 0; j < c; j += 8) {
        h4 hB = *(const h4*)(Y + (size_t)rC.x * 32 + l7 * 4);
        float ccB = (j + 8 + g < c) ? dinv[rC.x] * __uint_as_float(rC.y) : 0.f;
        int jn = j + 16 + g;
        uint2 rN = recs[st + (jn < c ? jn : c - 1)];
        #pragma unroll
        for (int k = 0; k < 4; ++k) acc[k] += ccA * (float)hA[k];
        hA = hB; ccA = ccB; rC = rN;
    }
    #pragma unroll
    for (int k = 0; k < 4; ++k) {
        acc[k] += __shfl_xor(acc[k], 8);
        acc[k] += __shfl_xor(acc[k], 16);
        acc[k] += __shfl_xor(acc[k], 32);
    }
    float dn = dinv[node], d2 = dn * dn;
    h4 hz = *(const h4*)(Y + (size_t)node * 32 + l7 * 4);
    bool live = (l7 < 5);                             // 5 lanes x 4 = 20 classes
    float tv[4];
    float mx = -INFINITY;
    #pragma unroll
    for (int k = 0; k < 4; ++k) {
        tv[k] = live ? (b2[l7 * 4 + k] + dn * acc[k] + d2 * (float)hz[k]) : -INFINITY;
        mx = fmaxf(mx, tv[k]);
    }
    #pragma unroll
    for (int off = 1; off <= 4; off <<= 1) mx = fmaxf(mx, __shfl_xor(mx, off));
    float ex = 0.f;
    if (live) {
        #pragma unroll
        for (int k = 0; k < 4; ++k) ex += expf(tv[k] - mx);
    }
    #pragma unroll
    for (int off = 1; off <= 4; off <<= 1) ex += __shfl_xor(ex, off);
    float ls = logf(ex);
    if (g == 0 && live) {
        float4 o;
        o.x = tv[0] - mx - ls; o.y = tv[1] - mx - ls;
        o.z = tv[2] - mx - ls; o.w = tv[3] - mx - ls;
        *(float4*)(out + (size_t)node * CDIM + l7 * 4) = o;
    }
}

// ---------------------------------------------------------------------------
extern "C" void kernel_launch(void* const* d_in, const int* in_sizes, int n_in,
                              void* d_out, int out_size, void* d_ws, size_t ws_size,
                              hipStream_t stream) {
    (void)in_sizes; (void)n_in; (void)out_size; (void)ws_size;
    const int*   node_ids = (const int*)d_in[0];
    const int*   e_src    = (const int*)d_in[1];
    const int*   e_dst    = e_src + N_EDGES;
    const float* edge_w   = (const float*)d_in[2];
    const float* emb      = (const float*)d_in[3];
    const float* W0       = (const float*)d_in[4];
    const float* b0       = (const float*)d_in[5];
    const float* W1       = (const float*)d_in[6];
    const float* b1       = (const float*)d_in[7];
    const float* W2       = (const float*)d_in[8];
    const float* b2       = (const float*)d_in[9];
    float* out = (float*)d_out;

    char* w = (char*)d_ws;
    size_t off = 0;
    auto alloc = [&](size_t bytes) {
        void* p = w + off;
        off = (off + bytes + 255) & ~(size_t)255;
        return p;
    };
    f16*   xA     = (f16*)alloc((size_t)N_NODES * FDIM * 2);     // 25.6 MB
    f16*   xB     = (f16*)alloc((size_t)N_NODES * FDIM * 2);     // 25.6 MB
    f16*   ybuf   = (f16*)alloc((size_t)N_NODES * 32 * 2);       // 6.4 MB
    int*   histG  = (int*)alloc((size_t)NB * NPART * 4);         // 800 KB
    int*   ptot   = (int*)alloc((size_t)NPART * 4);
    int*   nstart = (int*)alloc((size_t)N_NODES * 4);
    int*   ncnt   = (int*)alloc((size_t)N_NODES * 4);
    float* dinv   = (float*)alloc((size_t)N_NODES * 4);
    f16*   W0T    = (f16*)alloc(16384 * 2);
    f16*   W1T    = (f16*)alloc(16384 * 2);
    f16*   W2T    = (f16*)alloc(32 * 128 * 2);
    uint2* recs   = (uint2*)alloc((size_t)NPART * PCAP * 8);     // 16.0 MB

    k1_build<<<NB + GATHER_BLOCKS + 128 + 16, 256, 0, stream>>>(
        node_ids, emb, xA, e_dst, histG, W0, W1, W2, W0T, W1T, W2T);
    k2_seed<<<(NPART + 3) / 4, 256, 0, stream>>>(histG, ptot);
    k3_scatter<<<NB, 256, 0, stream>>>(e_src, e_dst, edge_w, histG, recs);
    k4_repack<<<NPART, 256, 0, stream>>>(recs, ptot, nstart, ncnt, dinv);

    int fblocks = N_NODES / 32;                      // 3125 exact
    // layer 0:  x1 = leaky((A.x0) W0 + b0)          (agg+GEMM fused)
    fusedL0<<<fblocks, 256, 0, stream>>>(xA, dinv, nstart, ncnt, recs, W0T, b0, xB);
    // layer 1 + 128->20:  y = leaky((A.x1) W1 + b1) W2   (x2 never hits HBM)
    fusedL1<<<fblocks, 256, 0, stream>>>(xB, dinv, nstart, ncnt, recs, W1T, b1, W2T, ybuf);
    // out = LSM(b2 + A.y)
    agg20L<<<N_NODES / 4, 256, 0, stream>>>(ybuf, dinv, nstart, ncnt, recs, b2, out);
}